// Round 11
// baseline (236.863 us; speedup 1.0000x reference)
//
#include <hip/hip_runtime.h>

#define N_NODES 50000
#define NP (N_NODES / 2)               // 25000 packed node-pairs
#define N_EDGES 800000
#define D 128
#define NCH 128                        // edge chunks
#define EPC (N_EDGES / NCH)            // 6250 edges per chunk
#define NRB ((NP + 255) / 256)         // 98 reduce blocks (512 nodes each)
#define SCB ((N_NODES + 255) / 256)    // 196 scanC blocks
#define INB ((N_NODES * (D / 4) + 255) / 256)  // 6250 init blocks

typedef unsigned short ushort_t;
typedef unsigned int uint_t;
typedef short s16x8 __attribute__((ext_vector_type(8)));
typedef float f32x4 __attribute__((ext_vector_type(4)));

__device__ __forceinline__ float bf2f(ushort_t u) {
    uint_t x = ((uint_t)u) << 16;
    return __builtin_bit_cast(float, x);
}
__device__ __forceinline__ ushort_t f2bf(float f) {
    uint_t u = __builtin_bit_cast(uint_t, f);
    uint_t r = (u + 0x7FFFu + ((u >> 16) & 1u)) >> 16;   // round-to-nearest-even
    return (ushort_t)r;
}

// ---- pass 1: packed histograms (2 nodes/u32, 16-bit counts) + fused W-prep ----
// y==0: dst -> dhist[chunk]; y==1: src -> shist[chunk]; y==2: Wt = bf16(W^T)
__global__ __launch_bounds__(256) void kb_hist(const int* __restrict__ src,
        const int* __restrict__ dst, uint_t* __restrict__ dhist,
        uint_t* __restrict__ shist,
        const float* __restrict__ W1, const float* __restrict__ W2,
        ushort_t* __restrict__ Wt1, ushort_t* __restrict__ Wt2) {
    __shared__ uint_t h[NP];           // 100 KB
    if (blockIdx.y == 2) {             // W transpose+bf16: 64 blocks per matrix
        int x = blockIdx.x;
        const float* W = (x & 64) ? W2 : W1;
        ushort_t* Wt = (x & 64) ? Wt2 : Wt1;
        int i = (x & 63) * 256 + threadIdx.x;
        int col = i >> 7, k = i & 127;
        Wt[i] = f2bf(W[(size_t)k * D + col]);
        return;
    }
    int chunk = blockIdx.x;
    const int* arr = blockIdx.y ? src : dst;
    uint_t* out = (blockIdx.y ? shist : dhist) + (size_t)chunk * NP;
    int t = threadIdx.x;
    for (int i = t; i < NP; i += 256) h[i] = 0;
    __syncthreads();
    int e0 = chunk * EPC;
    for (int e = e0 + t; e < e0 + EPC; e += 256) {
        int n = arr[e];
        atomicAdd(&h[n >> 1], 1u << ((n & 1) * 16));
    }
    __syncthreads();
    for (int i = t; i < NP; i += 256) out[i] = h[i];
}

// ---- per node-pair: chunkbase (in-place, packed), norm/rnorm, 512-node block scan ----
__global__ __launch_bounds__(256) void kb_reduce(uint_t* __restrict__ dhist,
        const uint_t* __restrict__ shist,
        int* __restrict__ off, int* __restrict__ bsum,
        float* __restrict__ norm, float* __restrict__ rnorm) {
    __shared__ int sh[256];
    int t = threadIdx.x;
    int p = blockIdx.x * 256 + t;      // pair index: nodes 2p, 2p+1
    int run0 = 0, run1 = 0, od0 = 0, od1 = 0;
    if (p < NP) {
#pragma unroll 8
        for (int c = 0; c < NCH; ++c) {
            size_t idx = (size_t)c * NP + p;
            uint_t v = dhist[idx];
            dhist[idx] = (uint_t)(run0 | (run1 << 16));   // packed chunkbase
            run0 += (int)(v & 0xFFFFu);
            run1 += (int)(v >> 16);
            uint_t s = shist[idx];
            od0 += (int)(s & 0xFFFFu);
            od1 += (int)(s >> 16);
        }
        float dg0 = fmaxf((float)od0, 1.0f);
        float dg1 = fmaxf((float)od1, 1.0f);
        norm[2 * p]      = 1.0f / sqrtf(dg0);
        rnorm[2 * p]     = sqrtf(dg0);
        norm[2 * p + 1]  = 1.0f / sqrtf(dg1);
        rnorm[2 * p + 1] = sqrtf(dg1);
    }
    int tot = run0 + run1;
    sh[t] = tot;
    __syncthreads();
    for (int d = 1; d < 256; d <<= 1) {
        int x = sh[t];
        int y = (t >= d) ? sh[t - d] : 0;
        __syncthreads();
        sh[t] = x + y;
        __syncthreads();
    }
    if (p < NP) {
        int base = sh[t] - tot;        // exclusive within block
        off[2 * p]     = base;
        off[2 * p + 1] = base + run0;
    }
    if (t == 255) bsum[blockIdx.x] = sh[255];
}

// ---- fused: scanC (each block locally scans the 98 bsum entries) + layer-1 init ----
__global__ __launch_bounds__(256) void k_scanC_init(int* __restrict__ off,
        const int* __restrict__ bsum,
        const float* __restrict__ X, const float* __restrict__ norm,
        ushort_t* __restrict__ A) {
    int b = blockIdx.x;
    int t = threadIdx.x;
    if (b < SCB) {
        __shared__ int sh[128];
        sh[t & 127] = (t < NRB) ? bsum[t] : 0;   // threads 128.. redundant-write zeros? no:
        // only threads 0..127 define sh; guard:
        __syncthreads();
        if (t < 128) {
            int v = (t < NRB) ? bsum[t] : 0;
            sh[t] = v;
        }
        __syncthreads();
        for (int d = 1; d < 128; d <<= 1) {
            int x = (t < 128) ? sh[t] : 0;
            int y = (t >= d && t < 128) ? sh[t - d] : 0;
            __syncthreads();
            if (t < 128) sh[t] = x + y;
            __syncthreads();
        }
        // inclusive scan in sh; node i needs exclusive prefix of bsum[i>>9]
        int i = b * 256 + t;
        if (i < N_NODES) {
            int rb = i >> 9;           // reduce-block index
            int base = (rb > 0) ? sh[rb - 1] : 0;
            off[i] += base;
        }
        if (b == 0 && t == 0) off[N_NODES] = sh[NRB - 1];
    } else {
        int i = (b - SCB) * 256 + t;   // float4/ushort4 index
        const int total = N_NODES * (D / 4);
        if (i < total) {
            int row = i >> 5;
            float4 v = ((const float4*)X)[i];
            float nm = norm[row];
            ushort4 a = {f2bf(v.x * nm), f2bf(v.y * nm), f2bf(v.z * nm), f2bf(v.w * nm)};
            ((ushort4*)A)[i] = a;
        }
    }
}

// ---- pass 2: regenerate ranks in LDS, scatter csrc (no global atomics) ----
__global__ __launch_bounds__(256) void kb_scatter(const int* __restrict__ src,
        const int* __restrict__ dst, const int* __restrict__ off,
        const uint_t* __restrict__ dhist, int* __restrict__ csrc) {
    __shared__ int slot[NP];           // 100 KB
    int chunk = blockIdx.x, range = blockIdx.y;
    int base = range * NP;
    int t = threadIdx.x;
    const uint_t* hb = dhist + (size_t)chunk * NP + range * (NP / 2);
    for (int i = t; i < NP; i += 256) {
        uint_t cb = hb[i >> 1];
        int c16 = (int)((cb >> ((i & 1) * 16)) & 0xFFFFu);
        slot[i] = off[base + i] + c16;
    }
    __syncthreads();
    int e0 = chunk * EPC;
    for (int e = e0 + t; e < e0 + EPC; e += 256) {
        unsigned du = (unsigned)(dst[e] - base);
        if (du < (unsigned)NP) {
            int p = atomicAdd(&slot[du], 1);
            csrc[p] = src[e];
        }
    }
}

// ---- propagation hop: 16-lane group per node, 16 gathers in flight, idx prefetch ----
// mode 0 (hop 1): Aout = bf16(acc * norm^2) = A1 ; mode 1 (hop 2): Aout = bf16(acc*norm) = X2
__global__ __launch_bounds__(256, 2) void k_prop(const ushort_t* __restrict__ Ain,
                       const int* __restrict__ off, const int* __restrict__ csrc,
                       const float* __restrict__ norm,
                       ushort_t* __restrict__ Aout, int mode) {
    int w = blockIdx.x * 16 + (threadIdx.x >> 4);
    if (w >= N_NODES) return;
    int li = threadIdx.x & 15;         // 16B chunk within the 256B row
    int s0 = off[w], s1 = off[w + 1];
    float a0=0.f,a1=0.f,a2=0.f,a3=0.f,a4=0.f,a5=0.f,a6=0.f,a7=0.f;
    const s16x8* A8 = (const s16x8*)Ain;
    int jend = s0 + ((s1 - s0) & ~15);
    int idxA[16];
    if (jend > s0) {
#pragma unroll
        for (int k = 0; k < 16; ++k) idxA[k] = csrc[s0 + k];
    }
    for (int j = s0; j < jend; j += 16) {
        // issue 16 independent row gathers using current indices
        s16x8 v[16];
#pragma unroll
        for (int k = 0; k < 16; ++k) v[k] = A8[(size_t)idxA[k] * 16 + li];
        // prefetch next iteration's indices (hides csrc latency under gathers)
        int jn = j + 16;
        if (jn < jend) {
#pragma unroll
            for (int k = 0; k < 16; ++k) idxA[k] = csrc[jn + k];
        }
#pragma unroll
        for (int k = 0; k < 16; ++k) {
            a0 += bf2f((ushort_t)v[k][0]); a1 += bf2f((ushort_t)v[k][1]);
            a2 += bf2f((ushort_t)v[k][2]); a3 += bf2f((ushort_t)v[k][3]);
            a4 += bf2f((ushort_t)v[k][4]); a5 += bf2f((ushort_t)v[k][5]);
            a6 += bf2f((ushort_t)v[k][6]); a7 += bf2f((ushort_t)v[k][7]);
        }
    }
    // weighted tail (clamped loads are cache-hot; weight 0 kills contribution)
    if (jend < s1) {
        int e1 = s1 - 1;
        for (int j = jend; j < s1; j += 8) {
            int idx[8]; float wk[8];
#pragma unroll
            for (int k = 0; k < 8; ++k) {
                int jj = j + k;
                idx[k] = csrc[jj < s1 ? jj : e1];
                wk[k] = (jj < s1) ? 1.f : 0.f;
            }
            s16x8 v[8];
#pragma unroll
            for (int k = 0; k < 8; ++k) v[k] = A8[(size_t)idx[k] * 16 + li];
#pragma unroll
            for (int k = 0; k < 8; ++k) {
                a0 = fmaf(wk[k], bf2f((ushort_t)v[k][0]), a0);
                a1 = fmaf(wk[k], bf2f((ushort_t)v[k][1]), a1);
                a2 = fmaf(wk[k], bf2f((ushort_t)v[k][2]), a2);
                a3 = fmaf(wk[k], bf2f((ushort_t)v[k][3]), a3);
                a4 = fmaf(wk[k], bf2f((ushort_t)v[k][4]), a4);
                a5 = fmaf(wk[k], bf2f((ushort_t)v[k][5]), a5);
                a6 = fmaf(wk[k], bf2f((ushort_t)v[k][6]), a6);
                a7 = fmaf(wk[k], bf2f((ushort_t)v[k][7]), a7);
            }
        }
    }
    float nm = norm[w];
    float f = mode ? nm : nm * nm;
    s16x8 o;
    o[0] = (short)f2bf(a0 * f); o[1] = (short)f2bf(a1 * f);
    o[2] = (short)f2bf(a2 * f); o[3] = (short)f2bf(a3 * f);
    o[4] = (short)f2bf(a4 * f); o[5] = (short)f2bf(a5 * f);
    o[6] = (short)f2bf(a6 * f); o[7] = (short)f2bf(a7 * f);
    ((s16x8*)Aout)[(size_t)w * 16 + li] = o;
}

// ---- MFMA gemm: out = relu((X0 + A1*rnorm + X2) @ W + bscale*bias) ----
// X0 from X0f (f32) or X0h (bf16). Outputs any of: outf (f32), Hbf (bf16), Anext (bf16*norm).
__global__ __launch_bounds__(256) void k_gemm_relu(const float* __restrict__ X0f,
        const ushort_t* __restrict__ X0h,
        const ushort_t* __restrict__ A1, const ushort_t* __restrict__ X2,
        const float* __restrict__ rnorm,
        const ushort_t* __restrict__ Wt, const float* __restrict__ bias,
        float* __restrict__ outf, ushort_t* __restrict__ Hbf,
        ushort_t* __restrict__ Anext,
        const float* __restrict__ norm, float bscale) {
    __shared__ ushort_t Xs[64 * D];    // 16 KB, swizzled 16B chunks
    __shared__ ushort_t Ws[D * D];     // 32 KB, swizzled
    int t = threadIdx.x;
    int row0 = blockIdx.x * 64;
    // stage Wt -> Ws (swizzle chunk: pc = c ^ (row&7))
    const s16x8* Wg = (const s16x8*)Wt;
    s16x8* Ws8 = (s16x8*)Ws;
    for (int i = t; i < D * 16; i += 256) {
        int col = i >> 4, c = i & 15;
        Ws8[(col << 4) | (c ^ (col & 7))] = Wg[i];
    }
    // stage X = X0 + A1*rnorm + X2 -> bf16 swizzled
    s16x8* Xs8 = (s16x8*)Xs;
    for (int i = t; i < 64 * 16; i += 256) {
        int r = i >> 4, c = i & 15;    // chunk c: cols c*8..c*8+7
        int gr = row0 + r;
        s16x8 ov;
        if (gr < N_NODES) {
            size_t b4 = (size_t)gr * 32 + c * 2;
            float x[8];
            if (X0f) {
                float4 x0a = ((const float4*)X0f)[b4], x0b = ((const float4*)X0f)[b4 + 1];
                x[0]=x0a.x; x[1]=x0a.y; x[2]=x0a.z; x[3]=x0a.w;
                x[4]=x0b.x; x[5]=x0b.y; x[6]=x0b.z; x[7]=x0b.w;
            } else {
                ushort4 h0 = ((const ushort4*)X0h)[b4], h1 = ((const ushort4*)X0h)[b4 + 1];
                x[0]=bf2f(h0.x); x[1]=bf2f(h0.y); x[2]=bf2f(h0.z); x[3]=bf2f(h0.w);
                x[4]=bf2f(h1.x); x[5]=bf2f(h1.y); x[6]=bf2f(h1.z); x[7]=bf2f(h1.w);
            }
            ushort4 p0 = ((const ushort4*)A1)[b4], p1 = ((const ushort4*)A1)[b4 + 1];
            ushort4 q0 = ((const ushort4*)X2)[b4], q1 = ((const ushort4*)X2)[b4 + 1];
            float rn = rnorm[gr];
            ov[0] = (short)f2bf(x[0] + bf2f(p0.x) * rn + bf2f(q0.x));
            ov[1] = (short)f2bf(x[1] + bf2f(p0.y) * rn + bf2f(q0.y));
            ov[2] = (short)f2bf(x[2] + bf2f(p0.z) * rn + bf2f(q0.z));
            ov[3] = (short)f2bf(x[3] + bf2f(p0.w) * rn + bf2f(q0.w));
            ov[4] = (short)f2bf(x[4] + bf2f(p1.x) * rn + bf2f(q1.x));
            ov[5] = (short)f2bf(x[5] + bf2f(p1.y) * rn + bf2f(q1.y));
            ov[6] = (short)f2bf(x[6] + bf2f(p1.z) * rn + bf2f(q1.z));
            ov[7] = (short)f2bf(x[7] + bf2f(p1.w) * rn + bf2f(q1.w));
        } else {
            ov = (s16x8)0;
        }
        Xs8[(r << 4) | (c ^ (r & 7))] = ov;
    }
    __syncthreads();
    int wid = t >> 6, l = t & 63;
    int lrow = l & 15, lk = l >> 4;    // lk: k-group (8 bf16 each)
    f32x4 acc[8];
#pragma unroll
    for (int nt = 0; nt < 8; ++nt) acc[nt] = (f32x4){0.f, 0.f, 0.f, 0.f};
    const s16x8* Xr = (const s16x8*)Xs;
    const s16x8* Wr = (const s16x8*)Ws;
#pragma unroll
    for (int ks = 0; ks < 4; ++ks) {
        int kc = ks * 4 + lk;          // 16B chunk along k (k = kc*8)
        int ar = wid * 16 + lrow;      // A row
        s16x8 a = Xr[(ar << 4) | (kc ^ (ar & 7))];
#pragma unroll
        for (int nt = 0; nt < 8; ++nt) {
            int bc = nt * 16 + lrow;   // B col
            s16x8 b = Wr[(bc << 4) | (kc ^ (bc & 7))];
            acc[nt] = __builtin_amdgcn_mfma_f32_16x16x32_bf16(a, b, acc[nt], 0, 0, 0);
        }
    }
    // epilogue: C/D layout col = l&15, row = (l>>4)*4 + reg
    int rbase = row0 + wid * 16 + lk * 4;
#pragma unroll
    for (int nt = 0; nt < 8; ++nt) {
        int C = nt * 16 + lrow;
        float bv = bias[C] * bscale;
#pragma unroll
        for (int r = 0; r < 4; ++r) {
            int R = rbase + r;
            if (R < N_NODES) {
                float o = fmaxf(acc[nt][r] + bv, 0.f);
                size_t oi = (size_t)R * D + C;
                if (outf) outf[oi] = o;
                if (Hbf) Hbf[oi] = f2bf(o);
                if (Anext) Anext[oi] = f2bf(o * norm[R]);
            }
        }
    }
}

extern "C" void kernel_launch(void* const* d_in, const int* in_sizes, int n_in,
                              void* d_out, int out_size, void* d_ws, size_t ws_size,
                              hipStream_t stream) {
    const float* feat = (const float*)d_in[0];
    const float* W1   = (const float*)d_in[1];
    const float* b1   = (const float*)d_in[2];
    const float* W2   = (const float*)d_in[3];
    const float* b2   = (const float*)d_in[4];
    const int*   src  = (const int*)d_in[5];
    const int*   dst  = (const int*)d_in[6];
    float* out = (float*)d_out;

    char* ws = (char*)d_ws;
    size_t o = 0;
    auto alloc = [&](size_t bytes) {
        void* p = ws + o;
        o += (bytes + 1023) & ~(size_t)1023;
        return p;
    };
    uint_t*   dhist = (uint_t*)alloc((size_t)NCH * NP * 4);        // 12.8 MB
    uint_t*   shist = (uint_t*)alloc((size_t)NCH * NP * 4);        // 12.8 MB
    float*    norm  = (float*)alloc(N_NODES * 4);
    float*    rnorm = (float*)alloc(N_NODES * 4);
    int*      off   = (int*)alloc((N_NODES + 1) * 4);
    int*      bsum  = (int*)alloc(NRB * 4);
    int*      csrc  = (int*)alloc((size_t)N_EDGES * 4);
    ushort_t* bufA  = (ushort_t*)alloc((size_t)N_NODES * D * 2);   // A0
    ushort_t* bufB  = (ushort_t*)alloc((size_t)N_NODES * D * 2);   // A1
    ushort_t* bufC  = (ushort_t*)alloc((size_t)N_NODES * D * 2);   // X2
    ushort_t* bufD  = (ushort_t*)alloc((size_t)N_NODES * D * 2);   // H (bf16)
    ushort_t* Wt1   = (ushort_t*)alloc((size_t)D * D * 2);
    ushort_t* Wt2   = (ushort_t*)alloc((size_t)D * D * 2);
    (void)ws_size; (void)in_sizes; (void)n_in; (void)out_size;

    kb_hist<<<dim3(NCH, 3), 256, 0, stream>>>(src, dst, dhist, shist, W1, W2, Wt1, Wt2);
    kb_reduce<<<NRB, 256, 0, stream>>>(dhist, shist, off, bsum, norm, rnorm);
    k_scanC_init<<<SCB + INB, 256, 0, stream>>>(off, bsum, feat, norm, bufA);
    kb_scatter<<<dim3(NCH, 2), 256, 0, stream>>>(src, dst, off, dhist, csrc);

    const int prop_blocks = (N_NODES + 15) / 16;
    const int gemm_blocks = (N_NODES + 63) / 64;

    // ---- layer 1 ----
    k_prop<<<prop_blocks, 256, 0, stream>>>(bufA, off, csrc, norm, bufB, 0);   // A1
    k_prop<<<prop_blocks, 256, 0, stream>>>(bufB, off, csrc, norm, bufC, 1);   // X2
    // H = relu((feat + A1*rnorm + X2)W1 + 3b1) -> bf16 bufD; bufA = bf16(H*norm)
    k_gemm_relu<<<gemm_blocks, 256, 0, stream>>>(feat, nullptr, bufB, bufC, rnorm,
                                                 Wt1, b1, nullptr, bufD, bufA, norm, 3.0f);

    // ---- layer 2 ----
    k_prop<<<prop_blocks, 256, 0, stream>>>(bufA, off, csrc, norm, bufB, 0);   // A1
    k_prop<<<prop_blocks, 256, 0, stream>>>(bufB, off, csrc, norm, bufC, 1);   // X2
    k_gemm_relu<<<gemm_blocks, 256, 0, stream>>>(nullptr, bufD, bufB, bufC, rnorm,
                                                 Wt2, b2, out, nullptr, nullptr, norm, 3.0f);
}

// Round 12
// 226.017 us; speedup vs baseline: 1.0480x; 1.0480x over previous
//
#include <hip/hip_runtime.h>

#define N_NODES 50000
#define N_EDGES 800000
#define D 128
#define NSB ((N_NODES + 255) / 256)   // 196 scan blocks
#define NCH 128                        // edge chunks
#define EPC (N_EDGES / NCH)            // 6250 edges per chunk
#define NR 8                           // node ranges
#define RNG (N_NODES / NR)             // 6250 nodes per range

typedef unsigned short ushort_t;
typedef unsigned int uint_t;
typedef short s16x8 __attribute__((ext_vector_type(8)));
typedef float f32x4 __attribute__((ext_vector_type(4)));

__device__ __forceinline__ float bf2f(ushort_t u) {
    uint_t x = ((uint_t)u) << 16;
    return __builtin_bit_cast(float, x);
}
__device__ __forceinline__ ushort_t f2bf(float f) {
    uint_t u = __builtin_bit_cast(uint_t, f);
    uint_t r = (u + 0x7FFFu + ((u >> 16) & 1u)) >> 16;   // round-to-nearest-even
    return (ushort_t)r;
}

// ---- pass 1: packed per-chunk histograms (dst in lo16, src in hi16) ----
__global__ __launch_bounds__(256) void kb_hist(const int* __restrict__ src,
        const int* __restrict__ dst, uint_t* __restrict__ hist) {
    __shared__ uint_t h[RNG];          // 25 KB
    int chunk = blockIdx.x, range = blockIdx.y;
    int base = range * RNG;
    int t = threadIdx.x;
    for (int i = t; i < RNG; i += 256) h[i] = 0;
    __syncthreads();
    int e0 = chunk * EPC;
    for (int e = e0 + t; e < e0 + EPC; e += 256) {
        unsigned su = (unsigned)(src[e] - base);
        unsigned du = (unsigned)(dst[e] - base);
        if (su < RNG) atomicAdd(&h[su], 1u << 16);
        if (du < RNG) atomicAdd(&h[du], 1u);
    }
    __syncthreads();
    uint_t* oh = hist + (size_t)chunk * N_NODES + base;
    for (int i = t; i < RNG; i += 256) oh[i] = h[i];
}

// ---- per node: indeg, chunkbase (in-place), outdeg -> norm, rnorm ----
__global__ void kb_reduce(uint_t* __restrict__ hist, int* __restrict__ indeg,
                          float* __restrict__ norm, float* __restrict__ rnorm) {
    int n = blockIdx.x * 256 + threadIdx.x;
    if (n >= N_NODES) return;
    int run = 0, od = 0;
#pragma unroll 8
    for (int c = 0; c < NCH; ++c) {
        size_t idx = (size_t)c * N_NODES + n;
        uint_t v = hist[idx];
        hist[idx] = (uint_t)run;       // becomes within-node dst chunk-prefix
        run += (int)(v & 0xFFFFu);
        od  += (int)(v >> 16);
    }
    indeg[n] = run;
    float dg = fmaxf((float)od, 1.0f);
    norm[n]  = 1.0f / sqrtf(dg);
    rnorm[n] = sqrtf(dg);
}

// ---------------- two-level exclusive scan of indeg -> off ----------------
__global__ void k_scanA(const int* __restrict__ indeg, int* __restrict__ off,
                        int* __restrict__ bsum) {
    __shared__ int sh[256];
    int t = threadIdx.x;
    int i = blockIdx.x * 256 + t;
    int v = (i < N_NODES) ? indeg[i] : 0;
    sh[t] = v;
    __syncthreads();
    for (int d = 1; d < 256; d <<= 1) {
        int x = sh[t];
        int y = (t >= d) ? sh[t - d] : 0;
        __syncthreads();
        sh[t] = x + y;
        __syncthreads();
    }
    if (i < N_NODES) off[i] = sh[t] - v;
    if (t == 255) bsum[blockIdx.x] = sh[255];
}

__global__ void k_scanB(const int* __restrict__ bsum, int* __restrict__ bbase,
                        int* __restrict__ off) {
    __shared__ int sh[256];
    int t = threadIdx.x;
    int v = (t < NSB) ? bsum[t] : 0;
    sh[t] = v;
    __syncthreads();
    for (int d = 1; d < 256; d <<= 1) {
        int x = sh[t];
        int y = (t >= d) ? sh[t - d] : 0;
        __syncthreads();
        sh[t] = x + y;
        __syncthreads();
    }
    if (t < NSB) bbase[t] = sh[t] - v;
    if (t == 255) off[N_NODES] = sh[255];
}

__global__ void k_scanC(int* __restrict__ off, const int* __restrict__ bbase) {
    int i = blockIdx.x * 256 + threadIdx.x;
    if (i < N_NODES) off[i] += bbase[blockIdx.x];
}

// ---- pass 2: regenerate ranks in LDS, scatter csrc (no global atomics) ----
__global__ __launch_bounds__(256) void kb_scatter(const int* __restrict__ src,
        const int* __restrict__ dst, const int* __restrict__ off,
        const uint_t* __restrict__ hist, int* __restrict__ csrc) {
    __shared__ int slot[RNG];          // 25 KB
    int chunk = blockIdx.x, range = blockIdx.y;
    int base = range * RNG;
    int t = threadIdx.x;
    const uint_t* hb = hist + (size_t)chunk * N_NODES + base;
    for (int i = t; i < RNG; i += 256) slot[i] = off[base + i] + (int)(hb[i] & 0xFFFFu);
    __syncthreads();
    int e0 = chunk * EPC;
    for (int e = e0 + t; e < e0 + EPC; e += 256) {
        unsigned du = (unsigned)(dst[e] - base);
        if (du < RNG) {
            int p = atomicAdd(&slot[du], 1);
            csrc[p] = src[e];
        }
    }
}

// ---- W transpose + bf16 (both layers, one launch): Wt[col][k] = bf16(W[k][col]) ----
__global__ void k_prepw(const float* __restrict__ W1, const float* __restrict__ W2,
                        ushort_t* __restrict__ Wt1, ushort_t* __restrict__ Wt2) {
    int i = blockIdx.x * 256 + threadIdx.x;
    const float* W = blockIdx.y ? W2 : W1;
    ushort_t* Wt = blockIdx.y ? Wt2 : Wt1;
    if (i < D * D) {
        int col = i >> 7, k = i & 127;
        Wt[i] = f2bf(W[(size_t)k * D + col]);
    }
}

// ---------------- layer-1 init: A = bf16(X * norm) ----------------
__global__ void k_init(const float* __restrict__ X, const float* __restrict__ norm,
                       ushort_t* __restrict__ A) {
    int i = blockIdx.x * blockDim.x + threadIdx.x;  // float4 / ushort4 index
    const int total = N_NODES * (D / 4);
    if (i < total) {
        int row = i >> 5;
        float4 v = ((const float4*)X)[i];
        float nm = norm[row];
        ushort4 a = {f2bf(v.x * nm), f2bf(v.y * nm), f2bf(v.z * nm), f2bf(v.w * nm)};
        ((ushort4*)A)[i] = a;
    }
}

// ---- propagation hop: 16-lane group per node, 16 b128 gathers in flight ----
// mode 0 (hop 1): Aout = bf16(acc * norm^2) = A1 ; mode 1 (hop 2): Aout = bf16(acc*norm) = X2
__global__ __launch_bounds__(256, 2) void k_prop(const ushort_t* __restrict__ Ain,
                       const int* __restrict__ off, const int* __restrict__ csrc,
                       const float* __restrict__ norm,
                       ushort_t* __restrict__ Aout, int mode) {
    int w = blockIdx.x * 16 + (threadIdx.x >> 4);
    if (w >= N_NODES) return;
    int li = threadIdx.x & 15;         // 16B chunk within the 256B row
    int s0 = off[w], s1 = off[w + 1];
    float a0=0.f,a1=0.f,a2=0.f,a3=0.f,a4=0.f,a5=0.f,a6=0.f,a7=0.f;
    const s16x8* A8 = (const s16x8*)Ain;
    int j = s0;
    // main loop: 16 independent row gathers in flight
    for (; j + 16 <= s1; j += 16) {
        int idx[16];
#pragma unroll
        for (int k = 0; k < 16; ++k) idx[k] = csrc[j + k];
        s16x8 v[16];
#pragma unroll
        for (int k = 0; k < 16; ++k) v[k] = A8[(size_t)idx[k] * 16 + li];
#pragma unroll
        for (int k = 0; k < 16; ++k) {
            a0 += bf2f((ushort_t)v[k][0]); a1 += bf2f((ushort_t)v[k][1]);
            a2 += bf2f((ushort_t)v[k][2]); a3 += bf2f((ushort_t)v[k][3]);
            a4 += bf2f((ushort_t)v[k][4]); a5 += bf2f((ushort_t)v[k][5]);
            a6 += bf2f((ushort_t)v[k][6]); a7 += bf2f((ushort_t)v[k][7]);
        }
    }
    // weighted tail (clamped loads are L1-hot; weight 0 kills contribution)
    if (j < s1) {
        int e1 = s1 - 1;
        for (; j < s1; j += 8) {
            int idx[8]; float wk[8];
#pragma unroll
            for (int k = 0; k < 8; ++k) {
                int jj = j + k;
                idx[k] = csrc[jj < s1 ? jj : e1];
                wk[k] = (jj < s1) ? 1.f : 0.f;
            }
            s16x8 v[8];
#pragma unroll
            for (int k = 0; k < 8; ++k) v[k] = A8[(size_t)idx[k] * 16 + li];
#pragma unroll
            for (int k = 0; k < 8; ++k) {
                a0 = fmaf(wk[k], bf2f((ushort_t)v[k][0]), a0);
                a1 = fmaf(wk[k], bf2f((ushort_t)v[k][1]), a1);
                a2 = fmaf(wk[k], bf2f((ushort_t)v[k][2]), a2);
                a3 = fmaf(wk[k], bf2f((ushort_t)v[k][3]), a3);
                a4 = fmaf(wk[k], bf2f((ushort_t)v[k][4]), a4);
                a5 = fmaf(wk[k], bf2f((ushort_t)v[k][5]), a5);
                a6 = fmaf(wk[k], bf2f((ushort_t)v[k][6]), a6);
                a7 = fmaf(wk[k], bf2f((ushort_t)v[k][7]), a7);
            }
        }
    }
    float nm = norm[w];
    float f = mode ? nm : nm * nm;
    s16x8 o;
    o[0] = (short)f2bf(a0 * f); o[1] = (short)f2bf(a1 * f);
    o[2] = (short)f2bf(a2 * f); o[3] = (short)f2bf(a3 * f);
    o[4] = (short)f2bf(a4 * f); o[5] = (short)f2bf(a5 * f);
    o[6] = (short)f2bf(a6 * f); o[7] = (short)f2bf(a7 * f);
    ((s16x8*)Aout)[(size_t)w * 16 + li] = o;
}

// ---- MFMA gemm: out = relu((X0 + A1*rnorm + X2) @ W + bscale*bias) ----
// X0 from X0f (f32) or X0h (bf16). Outputs any of: outf (f32), Hbf (bf16), Anext (bf16*norm).
__global__ __launch_bounds__(256) void k_gemm_relu(const float* __restrict__ X0f,
        const ushort_t* __restrict__ X0h,
        const ushort_t* __restrict__ A1, const ushort_t* __restrict__ X2,
        const float* __restrict__ rnorm,
        const ushort_t* __restrict__ Wt, const float* __restrict__ bias,
        float* __restrict__ outf, ushort_t* __restrict__ Hbf,
        ushort_t* __restrict__ Anext,
        const float* __restrict__ norm, float bscale) {
    __shared__ ushort_t Xs[64 * D];    // 16 KB, swizzled 16B chunks
    __shared__ ushort_t Ws[D * D];     // 32 KB, swizzled
    int t = threadIdx.x;
    int row0 = blockIdx.x * 64;
    // stage Wt -> Ws (swizzle chunk: pc = c ^ (row&7))
    const s16x8* Wg = (const s16x8*)Wt;
    s16x8* Ws8 = (s16x8*)Ws;
    for (int i = t; i < D * 16; i += 256) {
        int col = i >> 4, c = i & 15;
        Ws8[(col << 4) | (c ^ (col & 7))] = Wg[i];
    }
    // stage X = X0 + A1*rnorm + X2 -> bf16 swizzled
    s16x8* Xs8 = (s16x8*)Xs;
    for (int i = t; i < 64 * 16; i += 256) {
        int r = i >> 4, c = i & 15;    // chunk c: cols c*8..c*8+7
        int gr = row0 + r;
        s16x8 ov;
        if (gr < N_NODES) {
            size_t b4 = (size_t)gr * 32 + c * 2;
            float x[8];
            if (X0f) {
                float4 x0a = ((const float4*)X0f)[b4], x0b = ((const float4*)X0f)[b4 + 1];
                x[0]=x0a.x; x[1]=x0a.y; x[2]=x0a.z; x[3]=x0a.w;
                x[4]=x0b.x; x[5]=x0b.y; x[6]=x0b.z; x[7]=x0b.w;
            } else {
                ushort4 h0 = ((const ushort4*)X0h)[b4], h1 = ((const ushort4*)X0h)[b4 + 1];
                x[0]=bf2f(h0.x); x[1]=bf2f(h0.y); x[2]=bf2f(h0.z); x[3]=bf2f(h0.w);
                x[4]=bf2f(h1.x); x[5]=bf2f(h1.y); x[6]=bf2f(h1.z); x[7]=bf2f(h1.w);
            }
            ushort4 p0 = ((const ushort4*)A1)[b4], p1 = ((const ushort4*)A1)[b4 + 1];
            ushort4 q0 = ((const ushort4*)X2)[b4], q1 = ((const ushort4*)X2)[b4 + 1];
            float rn = rnorm[gr];
            ov[0] = (short)f2bf(x[0] + bf2f(p0.x) * rn + bf2f(q0.x));
            ov[1] = (short)f2bf(x[1] + bf2f(p0.y) * rn + bf2f(q0.y));
            ov[2] = (short)f2bf(x[2] + bf2f(p0.z) * rn + bf2f(q0.z));
            ov[3] = (short)f2bf(x[3] + bf2f(p0.w) * rn + bf2f(q0.w));
            ov[4] = (short)f2bf(x[4] + bf2f(p1.x) * rn + bf2f(q1.x));
            ov[5] = (short)f2bf(x[5] + bf2f(p1.y) * rn + bf2f(q1.y));
            ov[6] = (short)f2bf(x[6] + bf2f(p1.z) * rn + bf2f(q1.z));
            ov[7] = (short)f2bf(x[7] + bf2f(p1.w) * rn + bf2f(q1.w));
        } else {
            ov = (s16x8)0;
        }
        Xs8[(r << 4) | (c ^ (r & 7))] = ov;
    }
    __syncthreads();
    int wid = t >> 6, l = t & 63;
    int lrow = l & 15, lk = l >> 4;    // lk: k-group (8 bf16 each)
    f32x4 acc[8];
#pragma unroll
    for (int nt = 0; nt < 8; ++nt) acc[nt] = (f32x4){0.f, 0.f, 0.f, 0.f};
    const s16x8* Xr = (const s16x8*)Xs;
    const s16x8* Wr = (const s16x8*)Ws;
#pragma unroll
    for (int ks = 0; ks < 4; ++ks) {
        int kc = ks * 4 + lk;          // 16B chunk along k (k = kc*8)
        int ar = wid * 16 + lrow;      // A row
        s16x8 a = Xr[(ar << 4) | (kc ^ (ar & 7))];
#pragma unroll
        for (int nt = 0; nt < 8; ++nt) {
            int bc = nt * 16 + lrow;   // B col
            s16x8 b = Wr[(bc << 4) | (kc ^ (bc & 7))];
            acc[nt] = __builtin_amdgcn_mfma_f32_16x16x32_bf16(a, b, acc[nt], 0, 0, 0);
        }
    }
    // epilogue: C/D layout col = l&15, row = (l>>4)*4 + reg
    int rbase = row0 + wid * 16 + lk * 4;
#pragma unroll
    for (int nt = 0; nt < 8; ++nt) {
        int C = nt * 16 + lrow;
        float bv = bias[C] * bscale;
#pragma unroll
        for (int r = 0; r < 4; ++r) {
            int R = rbase + r;
            if (R < N_NODES) {
                float o = fmaxf(acc[nt][r] + bv, 0.f);
                size_t oi = (size_t)R * D + C;
                if (outf) outf[oi] = o;
                if (Hbf) Hbf[oi] = f2bf(o);
                if (Anext) Anext[oi] = f2bf(o * norm[R]);
            }
        }
    }
}

extern "C" void kernel_launch(void* const* d_in, const int* in_sizes, int n_in,
                              void* d_out, int out_size, void* d_ws, size_t ws_size,
                              hipStream_t stream) {
    const float* feat = (const float*)d_in[0];
    const float* W1   = (const float*)d_in[1];
    const float* b1   = (const float*)d_in[2];
    const float* W2   = (const float*)d_in[3];
    const float* b2   = (const float*)d_in[4];
    const int*   src  = (const int*)d_in[5];
    const int*   dst  = (const int*)d_in[6];
    float* out = (float*)d_out;

    char* ws = (char*)d_ws;
    size_t o = 0;
    auto alloc = [&](size_t bytes) {
        void* p = ws + o;
        o += (bytes + 1023) & ~(size_t)1023;
        return p;
    };
    uint_t*   hist  = (uint_t*)alloc((size_t)NCH * N_NODES * 4);   // 25.6 MB
    int*      indeg = (int*)alloc(N_NODES * 4);
    float*    norm  = (float*)alloc(N_NODES * 4);
    float*    rnorm = (float*)alloc(N_NODES * 4);
    int*      off   = (int*)alloc((N_NODES + 1) * 4);
    int*      bsum  = (int*)alloc(NSB * 4);
    int*      bbase = (int*)alloc(NSB * 4);
    int*      csrc  = (int*)alloc((size_t)N_EDGES * 4);
    ushort_t* bufA  = (ushort_t*)alloc((size_t)N_NODES * D * 2);   // A0
    ushort_t* bufB  = (ushort_t*)alloc((size_t)N_NODES * D * 2);   // A1
    ushort_t* bufC  = (ushort_t*)alloc((size_t)N_NODES * D * 2);   // X2
    ushort_t* bufD  = (ushort_t*)alloc((size_t)N_NODES * D * 2);   // H (bf16)
    ushort_t* Wt1   = (ushort_t*)alloc((size_t)D * D * 2);
    ushort_t* Wt2   = (ushort_t*)alloc((size_t)D * D * 2);
    (void)ws_size; (void)in_sizes; (void)n_in; (void)out_size;

    kb_hist<<<dim3(NCH, NR), 256, 0, stream>>>(src, dst, hist);
    kb_reduce<<<(N_NODES + 255) / 256, 256, 0, stream>>>(hist, indeg, norm, rnorm);
    k_scanA<<<NSB, 256, 0, stream>>>(indeg, off, bsum);
    k_scanB<<<1, 256, 0, stream>>>(bsum, bbase, off);
    k_scanC<<<NSB, 256, 0, stream>>>(off, bbase);
    kb_scatter<<<dim3(NCH, NR), 256, 0, stream>>>(src, dst, off, hist, csrc);
    k_prepw<<<dim3((D * D + 255) / 256, 2), 256, 0, stream>>>(W1, W2, Wt1, Wt2);

    const int init_blocks = (N_NODES * 32 + 255) / 256;
    const int prop_blocks = (N_NODES + 15) / 16;
    const int gemm_blocks = (N_NODES + 63) / 64;

    // ---- layer 1 ----
    k_init<<<init_blocks, 256, 0, stream>>>(feat, norm, bufA);                 // A0
    k_prop<<<prop_blocks, 256, 0, stream>>>(bufA, off, csrc, norm, bufB, 0);   // A1
    k_prop<<<prop_blocks, 256, 0, stream>>>(bufB, off, csrc, norm, bufC, 1);   // X2
    // H = relu((feat + A1*rnorm + X2)W1 + 3b1) -> bf16 bufD; bufA = bf16(H*norm)
    k_gemm_relu<<<gemm_blocks, 256, 0, stream>>>(feat, nullptr, bufB, bufC, rnorm,
                                                 Wt1, b1, nullptr, bufD, bufA, norm, 3.0f);

    // ---- layer 2 ----
    k_prop<<<prop_blocks, 256, 0, stream>>>(bufA, off, csrc, norm, bufB, 0);   // A1
    k_prop<<<prop_blocks, 256, 0, stream>>>(bufB, off, csrc, norm, bufC, 1);   // X2
    k_gemm_relu<<<gemm_blocks, 256, 0, stream>>>(nullptr, bufD, bufB, bufC, rnorm,
                                                 Wt2, b2, out, nullptr, nullptr, norm, 3.0f);
}